// Round 11
// baseline (313.877 us; speedup 1.0000x reference)
//
#include <hip/hip_runtime.h>
#include <hip/hip_bf16.h>
#include <math.h>

#define DIM 384
#define HEADS 6
#define HIDDEN 1536
#define NTOK 2744   // 14*14*14
#define BATCH 2
#define MTOT (BATCH * NTOK)   // 5488
#define KSPLIT 3
#define NQT 22      // ceil(2744/128)
#define CEXP 0.18033688f   // (1/8) * log2(e)

typedef __bf16 bf16x8 __attribute__((ext_vector_type(8)));
typedef __bf16 bf16x4 __attribute__((ext_vector_type(4)));
typedef float  f32x4  __attribute__((ext_vector_type(4)));

#define F_GELU  1
#define F_BF16  4
#define F_QKV   8

// async global->LDS, 16B per lane; LDS dest = uniform base + lane*16
__device__ __forceinline__ void gll16(const void* g, void* l) {
    __builtin_amdgcn_global_load_lds(
        (const __attribute__((address_space(1))) unsigned int*)g,
        (__attribute__((address_space(3))) unsigned int*)l, 16, 0, 0);
}

// ---------------------------------------------------------------------------
// k_conv: fused depthwise conv3d (+residual, NCDHW -> t[token,C] fp32)
// and weight fp32->bf16 conversion (tail blocks).
// ---------------------------------------------------------------------------
__global__ void k_conv(const float* __restrict__ x, const float* __restrict__ cw,
                       float* __restrict__ t,
                       const float* __restrict__ w0, const float* __restrict__ w1,
                       const float* __restrict__ w2, const float* __restrict__ w3,
                       __bf16* o0, __bf16* o1, __bf16* o2, __bf16* o3) {
    int bid = blockIdx.x;
    if (bid >= 8448) {   // ---- weight conversion ----
        int i = (bid - 8448) * 256 + threadIdx.x;   // float4 index
        const float* s; __bf16* d; int off;
        if (i < 110592)      { s = w0; d = o0; off = i; }
        else if (i < 147456) { s = w1; d = o1; off = i - 110592; }
        else if (i < 294912) { s = w2; d = o2; off = i - 147456; }
        else                 { s = w3; d = o3; off = i - 294912; }
        float4 v = ((const float4*)s)[off];
        bf16x4 bb = { (__bf16)v.x, (__bf16)v.y, (__bf16)v.z, (__bf16)v.w };
        *(bf16x4*)(d + (size_t)off * 4) = bb;
        return;
    }
    int nb = bid % 11, rest = bid / 11;
    int c = rest % 384, b = rest / 384;
    int n = nb * 256 + threadIdx.x;
    if (n >= NTOK) return;
    int d = n / 196, r = n % 196, h = r / 14, w = r % 14;
    const float* xp = x + ((size_t)b * DIM + c) * NTOK;
    const float* wp = cw + c * 27;
    float acc = xp[n];   // residual (conv_b cancels in reference)
    #pragma unroll
    for (int kd = 0; kd < 3; kd++) {
        int dd = d + kd - 1;
        if (dd < 0 || dd >= 14) continue;
        #pragma unroll
        for (int kh = 0; kh < 3; kh++) {
            int hh = h + kh - 1;
            if (hh < 0 || hh >= 14) continue;
            #pragma unroll
            for (int kw = 0; kw < 3; kw++) {
                int ww = w + kw - 1;
                if (ww < 0 || ww >= 14) continue;
                acc += wp[kd * 9 + kh * 3 + kw] * xp[(dd * 14 + hh) * 14 + ww];
            }
        }
    }
    t[((size_t)(b * NTOK + n)) * DIM + c] = acc;
}

// ---------------------------------------------------------------------------
// k_ln1: LayerNorm fp32 in -> bf16 out. One wave per token.
// ---------------------------------------------------------------------------
__global__ void k_ln1(const float* __restrict__ in, __bf16* __restrict__ out,
                      const float* __restrict__ w, const float* __restrict__ b) {
    int wid = threadIdx.x >> 6, lane = threadIdx.x & 63;
    int token = blockIdx.x * 4 + wid;
    const float* row = in + (size_t)token * DIM;
    float v[6], s = 0.f, s2 = 0.f;
    #pragma unroll
    for (int i = 0; i < 6; i++) {
        v[i] = row[lane + 64 * i];
        s += v[i]; s2 += v[i] * v[i];
    }
    #pragma unroll
    for (int m = 1; m < 64; m <<= 1) { s += __shfl_xor(s, m); s2 += __shfl_xor(s2, m); }
    float mu = s * (1.f / DIM);
    float rstd = rsqrtf(s2 * (1.f / DIM) - mu * mu + 1e-5f);
    __bf16* orow = out + (size_t)token * DIM;
    #pragma unroll
    for (int i = 0; i < 6; i++) {
        int c = lane + 64 * i;
        orow[c] = (__bf16)((v[i] - mu) * rstd * w[c] + b[c]);
    }
}

// ---------------------------------------------------------------------------
// gemm128 body: 128x128x64 tile, dbuf gll16, XOR swizzle (QKV, FC1).
// ---------------------------------------------------------------------------
__device__ __forceinline__ void gemm128_body(
    const __bf16* __restrict__ A, const __bf16* __restrict__ B,
    const float* __restrict__ bias, void* __restrict__ out,
    __bf16* __restrict__ vt_out, int M, int N, int K, int flags) {
    __shared__ __bf16 As[2][128][64];   // 32 KB
    __shared__ __bf16 Bs[2][128][64];   // 32 KB
    int tid = threadIdx.x, lane = tid & 63, wid = tid >> 6;
    int quad = lane >> 4, l16 = lane & 15;
    int wm = wid & 1, wn = wid >> 1;
    int m0 = blockIdx.y * 128, n0 = blockIdx.x * 128;
    int x7 = l16 & 7;

    auto stage = [&](int k0, int buf) {
        #pragma unroll
        for (int i = 0; i < 4; i++) {
            int c = i * 256 + tid;
            int row = c >> 3, cc = (c & 7) ^ (row & 7);
            int gm = m0 + row; if (gm > M - 1) gm = M - 1;
            gll16(A + (size_t)gm * K + k0 + cc * 8, &As[buf][0][0] + (size_t)c * 8);
        }
        #pragma unroll
        for (int i = 0; i < 4; i++) {
            int c = i * 256 + tid;
            int row = c >> 3, cc = (c & 7) ^ (row & 7);
            gll16(B + (size_t)(n0 + row) * K + k0 + cc * 8, &Bs[buf][0][0] + (size_t)c * 8);
        }
    };

    f32x4 acc[4][4] = {};
    int nk = K >> 6;
    stage(0, 0);
    __syncthreads();
    for (int ki = 0; ki < nk; ki++) {
        int cur = ki & 1;
        if (ki + 1 < nk) stage((ki + 1) << 6, cur ^ 1);
        #pragma unroll
        for (int s = 0; s < 2; s++) {
            bf16x8 a[4], b[4];
            #pragma unroll
            for (int i = 0; i < 4; i++)
                a[i] = *(bf16x8*)&As[cur][wm * 64 + i * 16 + l16][(((s * 4 + quad) ^ x7)) * 8];
            #pragma unroll
            for (int j = 0; j < 4; j++)
                b[j] = *(bf16x8*)&Bs[cur][wn * 64 + j * 16 + l16][(((s * 4 + quad) ^ x7)) * 8];
            #pragma unroll
            for (int i = 0; i < 4; i++)
                #pragma unroll
                for (int j = 0; j < 4; j++)
                    acc[i][j] = __builtin_amdgcn_mfma_f32_16x16x32_bf16(a[i], b[j], acc[i][j], 0, 0, 0);
        }
        __syncthreads();
    }

    #pragma unroll
    for (int j = 0; j < 4; j++) {
        int col = n0 + wn * 64 + j * 16 + l16;
        float bv = bias ? bias[col] : 0.f;
        #pragma unroll
        for (int i = 0; i < 4; i++) {
            int row0 = m0 + wm * 64 + i * 16 + quad * 4;
            if (row0 >= M) continue;
            float v4[4];
            #pragma unroll
            for (int r = 0; r < 4; r++) {
                float v = acc[i][j][r] + bv;
                if (flags & F_GELU) v = 0.5f * v * (1.f + erff(v * 0.70710678f));
                if ((flags & F_QKV) && col < 384) v *= CEXP;   // pre-scale Q
                v4[r] = v;
            }
            if ((flags & F_QKV) && col >= 768) {
                int b2 = row0 / NTOK, n2 = row0 - b2 * NTOK;
                bf16x4 pk = { (__bf16)v4[0], (__bf16)v4[1], (__bf16)v4[2], (__bf16)v4[3] };
                *(bf16x4*)(vt_out + ((size_t)(b2 * DIM + (col - 768))) * NTOK + n2) = pk;
            } else {
                #pragma unroll
                for (int r = 0; r < 4; r++)
                    ((__bf16*)out)[(size_t)(row0 + r) * N + col] = (__bf16)v4[r];
            }
        }
    }
}
__global__ __launch_bounds__(256) void k_qkv(const __bf16* A, const __bf16* B,
        void* out, __bf16* vt_out, int M, int N, int K) {
    gemm128_body(A, B, nullptr, out, vt_out, M, N, K, F_QKV);
}
__global__ __launch_bounds__(256) void k_fc1(const __bf16* A, const __bf16* B,
        const float* bias, void* out, int M, int N, int K) {
    gemm128_body(A, B, bias, out, nullptr, M, N, K, F_GELU | F_BF16);
}

// ---------------------------------------------------------------------------
// k_fc2: 64x64x64 tile, resid + transposed fp32 store.
// ---------------------------------------------------------------------------
__global__ __launch_bounds__(256) void k_fc2(
    const __bf16* __restrict__ A, const __bf16* __restrict__ B,
    const float* __restrict__ bias, const float* __restrict__ resid,
    float* __restrict__ out, int M, int N, int K) {
    __shared__ __bf16 As[2][64][64];   // 16 KB
    __shared__ __bf16 Bs[2][64][64];   // 16 KB
    int tid = threadIdx.x, lane = tid & 63, wid = tid >> 6;
    int quad = lane >> 4, l16 = lane & 15;
    int wm = wid & 1, wn = wid >> 1;
    int m0 = blockIdx.y * 64, n0 = blockIdx.x * 64;
    int x7 = l16 & 7;

    auto stage = [&](int k0, int buf) {
        #pragma unroll
        for (int i = 0; i < 2; i++) {
            int c = i * 256 + tid;
            int row = c >> 3, cc = (c & 7) ^ (row & 7);
            int gm = m0 + row; if (gm > M - 1) gm = M - 1;
            gll16(A + (size_t)gm * K + k0 + cc * 8, &As[buf][0][0] + (size_t)c * 8);
        }
        #pragma unroll
        for (int i = 0; i < 2; i++) {
            int c = i * 256 + tid;
            int row = c >> 3, cc = (c & 7) ^ (row & 7);
            gll16(B + (size_t)(n0 + row) * K + k0 + cc * 8, &Bs[buf][0][0] + (size_t)c * 8);
        }
    };

    f32x4 acc[2][2] = {};
    int nk = K >> 6;
    stage(0, 0);
    __syncthreads();
    for (int ki = 0; ki < nk; ki++) {
        int cur = ki & 1;
        if (ki + 1 < nk) stage((ki + 1) << 6, cur ^ 1);
        #pragma unroll
        for (int s = 0; s < 2; s++) {
            bf16x8 a[2], b[2];
            #pragma unroll
            for (int i = 0; i < 2; i++)
                a[i] = *(bf16x8*)&As[cur][wm * 32 + i * 16 + l16][(((s * 4 + quad) ^ x7)) * 8];
            #pragma unroll
            for (int j = 0; j < 2; j++)
                b[j] = *(bf16x8*)&Bs[cur][wn * 32 + j * 16 + l16][(((s * 4 + quad) ^ x7)) * 8];
            #pragma unroll
            for (int i = 0; i < 2; i++)
                #pragma unroll
                for (int j = 0; j < 2; j++)
                    acc[i][j] = __builtin_amdgcn_mfma_f32_16x16x32_bf16(a[i], b[j], acc[i][j], 0, 0, 0);
        }
        __syncthreads();
    }

    #pragma unroll
    for (int j = 0; j < 2; j++) {
        int col = n0 + wn * 32 + j * 16 + l16;
        float bv = bias[col];
        #pragma unroll
        for (int i = 0; i < 2; i++) {
            int row0 = m0 + wm * 32 + i * 16 + quad * 4;
            if (row0 >= M) continue;
            float v4[4];
            #pragma unroll
            for (int r = 0; r < 4; r++)
                v4[r] = acc[i][j][r] + bv + resid[(size_t)(row0 + r) * N + col];
            int b2 = row0 / NTOK, n2 = row0 - b2 * NTOK;
            float4 pk = { v4[0], v4[1], v4[2], v4[3] };
            *(float4*)(out + ((size_t)(b2 * N + col)) * NTOK + n2) = pk;
        }
    }
}

// ---------------------------------------------------------------------------
// k_attn: bf16 MFMA flash attention (R10-proven): 4 waves x 32 queries,
// single-buffered K/V (34.8 KB LDS), Ps padded stride 72 overlays Q staging,
// Q pre-scaled by CEXP, unnormalized exp + split-K partials.
// ---------------------------------------------------------------------------
__global__ __launch_bounds__(256) void k_attn(const __bf16* __restrict__ qkv,
                                              const __bf16* __restrict__ vt,
                                              float* __restrict__ opart,
                                              float* __restrict__ lpart) {
    __shared__ __align__(16) char smemQP[128 * 72 * 2];   // 18 KB: Q stage, then Ps
    __shared__ __bf16 Ks[64][64];    // 8 KB
    __shared__ __bf16 Vt[64][64];    // 8 KB
    __bf16 (*Qs)[64] = (__bf16(*)[64])smemQP;
    __bf16 (*Ps)[72] = (__bf16(*)[72])smemQP;

    int tid = threadIdx.x, lane = tid & 63, wid = tid >> 6;
    int quad = lane >> 4, l16 = lane & 15;
    int q0 = blockIdx.x * 128;
    int bh = blockIdx.y;
    int ks = blockIdx.z;
    int b = bh / HEADS, h = bh % HEADS;
    int x7 = l16 & 7;

    auto stageKV = [&](int k0) {
        #pragma unroll
        for (int i = 0; i < 2; i++) {
            int c = i * 256 + tid;
            int row = c >> 3, cc = (c & 7) ^ (row & 7);
            int gk = k0 + row; if (gk > NTOK - 1) gk = NTOK - 1;
            gll16(qkv + ((size_t)(b * NTOK + gk)) * 1152 + 384 + h * 64 + cc * 8,
                  &Ks[0][0] + (size_t)c * 8);
            gll16(vt + ((size_t)(bh * 64 + row)) * NTOK + k0 + cc * 8,
                  &Vt[0][0] + (size_t)c * 8);
        }
    };

    int kt0 = (43 * ks) / KSPLIT, kt1 = (43 * (ks + 1)) / KSPLIT;

    #pragma unroll
    for (int i = 0; i < 4; i++) {
        int c = i * 256 + tid;
        int row = c >> 3, cc = (c & 7) ^ (row & 7);
        int gq = q0 + row; if (gq > NTOK - 1) gq = NTOK - 1;
        gll16(qkv + ((size_t)(b * NTOK + gq)) * 1152 + h * 64 + cc * 8,
              &Qs[0][0] + (size_t)c * 8);
    }
    stageKV(kt0 * 64);
    __syncthreads();

    bf16x8 aq[2][2];
    #pragma unroll
    for (int qt = 0; qt < 2; qt++)
        #pragma unroll
        for (int s = 0; s < 2; s++)
            aq[qt][s] = *(bf16x8*)&Qs[wid * 32 + qt * 16 + l16][((s * 4 + quad) ^ x7) * 8];
    __syncthreads();   // Qs -> Ps overlay handoff

    f32x4 oacc[2][4] = {};
    float l_part[2][4] = {};
    __bf16* pwr = &Ps[wid * 32 + quad * 4][l16];
    const __bf16* prd = &Ps[wid * 32 + l16][0];

    for (int kt = kt0; kt < kt1; kt++) {
        if (kt > kt0) {
            __syncthreads();
            stageKV(kt * 64);
            __syncthreads();
        }
        int k0 = kt * 64;

        f32x4 s[2][4];
        #pragma unroll
        for (int t = 0; t < 4; t++) {
            bf16x8 bk0 = *(bf16x8*)&Ks[t * 16 + l16][((quad) ^ x7) * 8];
            bf16x8 bk1 = *(bf16x8*)&Ks[t * 16 + l16][((4 + quad) ^ x7) * 8];
            #pragma unroll
            for (int qt = 0; qt < 2; qt++) {
                f32x4 z = {0.f, 0.f, 0.f, 0.f};
                z = __builtin_amdgcn_mfma_f32_16x16x32_bf16(aq[qt][0], bk0, z, 0, 0, 0);
                s[qt][t] = __builtin_amdgcn_mfma_f32_16x16x32_bf16(aq[qt][1], bk1, z, 0, 0, 0);
            }
        }
        if (k0 + 64 > NTOK) {
            #pragma unroll
            for (int t = 0; t < 4; t++)
                if (k0 + t * 16 + l16 >= NTOK)
                    #pragma unroll
                    for (int qt = 0; qt < 2; qt++) {
                        s[qt][t][0] = -1e30f; s[qt][t][1] = -1e30f;
                        s[qt][t][2] = -1e30f; s[qt][t][3] = -1e30f;
                    }
        }
        #pragma unroll
        for (int qt = 0; qt < 2; qt++)
            #pragma unroll
            for (int t = 0; t < 4; t++)
                #pragma unroll
                for (int r = 0; r < 4; r++) {
                    float e = exp2f(s[qt][t][r]);   // scale folded into Q
                    l_part[qt][r] += e;
                    pwr[(qt * 16 + r) * 72 + t * 16] = (__bf16)e;
                }
        bf16x8 ap[2][2];
        #pragma unroll
        for (int qt = 0; qt < 2; qt++)
            #pragma unroll
            for (int sx = 0; sx < 2; sx++)
                ap[qt][sx] = *(bf16x8*)(prd + qt * 16 * 72 + sx * 32 + quad * 8);
        #pragma unroll
        for (int t = 0; t < 4; t++) {
            bf16x8 bv0 = *(bf16x8*)&Vt[t * 16 + l16][((quad) ^ x7) * 8];
            bf16x8 bv1 = *(bf16x8*)&Vt[t * 16 + l16][((4 + quad) ^ x7) * 8];
            #pragma unroll
            for (int qt = 0; qt < 2; qt++) {
                oacc[qt][t] = __builtin_amdgcn_mfma_f32_16x16x32_bf16(ap[qt][0], bv0, oacc[qt][t], 0, 0, 0);
                oacc[qt][t] = __builtin_amdgcn_mfma_f32_16x16x32_bf16(ap[qt][1], bv1, oacc[qt][t], 0, 0, 0);
            }
        }
    }

    #pragma unroll
    for (int qt = 0; qt < 2; qt++)
        #pragma unroll
        for (int r = 0; r < 4; r++) {
            int gq = q0 + wid * 32 + qt * 16 + quad * 4 + r;
            if (gq >= NTOK) continue;
            float l = l_part[qt][r];
            #pragma unroll
            for (int mk = 1; mk < 16; mk <<= 1) l += __shfl_xor(l, mk);
            if (l16 == 0) lpart[((size_t)ks * 12 + bh) * NTOK + gq] = l;
            float* op = opart + ((size_t)ks * MTOT + (size_t)b * NTOK + gq) * DIM + h * 64;
            #pragma unroll
            for (int t = 0; t < 4; t++) op[t * 16 + l16] = oacc[qt][t][r];
        }
}

// ---------------------------------------------------------------------------
// k_projln: fused split-K combine + proj GEMM + residual + LN2.
// Grid 86 blocks x 256 thr; block owns 64 tokens x ALL 384 cols.
// A (combined O) staged from OP/LP in-registers -> LDS (swizzled);
// B (WP) dbuf gll16 over 6 n-tiles. Epilogue: +bias +T resid -> T,
// then full-row LN (in-lane 24-partial + 16-lane shfl) -> TN bf16.
// Wave w owns token rows [w*16, w*16+16).
// ---------------------------------------------------------------------------
__global__ __launch_bounds__(256) void k_projln(
    const float* __restrict__ opart, const float* __restrict__ lpart,
    const __bf16* __restrict__ WP, const float* __restrict__ proj_b,
    const float* __restrict__ ln2w, const float* __restrict__ ln2b,
    float* __restrict__ T, __bf16* __restrict__ TN) {
    __shared__ __bf16 As[64][64];      //  8 KB
    __shared__ __bf16 Bs[2][64][64];   // 16 KB
    int tid = threadIdx.x, lane = tid & 63, wid = tid >> 6;
    int quad = lane >> 4, l16 = lane & 15, x7 = l16 & 7;
    int m0 = blockIdx.x * 64;

    auto stageB = [&](int k0, int n0, int buf) {
        #pragma unroll
        for (int i = 0; i < 2; i++) {
            int c = i * 256 + tid;
            int row = c >> 3, cc = (c & 7) ^ (row & 7);
            gll16(WP + (size_t)(n0 + row) * DIM + k0 + cc * 8,
                  &Bs[buf][0][0] + (size_t)c * 8);
        }
    };

    f32x4 acc[6][4] = {};

    for (int k = 0; k < 6; k++) {
        int k0 = k * 64, hh = k;   // head index = channel block
        __syncthreads();           // prior iter LDS reads done
        // stage A = (sum_ks OP) / (sum_ks l)  -> As (swizzled, bf16)
        #pragma unroll
        for (int i = 0; i < 2; i++) {
            int c = i * 256 + tid;
            int row = c >> 3, cc = (c & 7) ^ (row & 7);
            int gm = m0 + row; if (gm > MTOT - 1) gm = MTOT - 1;
            int b2 = gm / NTOK, gq = gm - b2 * NTOK;
            int bh = b2 * HEADS + hh;
            float l = 0.f;
            f32x4 s0 = {0.f, 0.f, 0.f, 0.f}, s1 = {0.f, 0.f, 0.f, 0.f};
            #pragma unroll
            for (int ks = 0; ks < KSPLIT; ks++) {
                const float* base = opart + ((size_t)ks * MTOT + gm) * DIM + k0 + cc * 8;
                f32x4 p0 = *(const f32x4*)base;
                f32x4 p1 = *(const f32x4*)(base + 4);
                s0[0] += p0[0]; s0[1] += p0[1]; s0[2] += p0[2]; s0[3] += p0[3];
                s1[0] += p1[0]; s1[1] += p1[1]; s1[2] += p1[2]; s1[3] += p1[3];
                l += lpart[((size_t)ks * 12 + bh) * NTOK + gq];
            }
            float inv = 1.f / l;
            bf16x8 pk = { (__bf16)(s0[0] * inv), (__bf16)(s0[1] * inv),
                          (__bf16)(s0[2] * inv), (__bf16)(s0[3] * inv),
                          (__bf16)(s1[0] * inv), (__bf16)(s1[1] * inv),
                          (__bf16)(s1[2] * inv), (__bf16)(s1[3] * inv) };
            *(bf16x8*)(&As[0][0] + (size_t)c * 8) = pk;
        }
        stageB(k0, 0, 0);
        __syncthreads();

        bf16x8 a[2];
        #pragma unroll
        for (int s = 0; s < 2; s++)
            a[s] = *(bf16x8*)&As[wid * 16 + l16][((s * 4 + quad) ^ x7) * 8];

        for (int n = 0; n < 6; n++) {
            int cur = n & 1;
            if (n + 1 < 6) stageB(k0, (n + 1) * 64, cur ^ 1);
            #pragma unroll
            for (int s = 0; s < 2; s++) {
                bf16x8 b[4];
                #pragma unroll
                for (int j = 0; j < 4; j++)
                    b[j] = *(bf16x8*)&Bs[cur][j * 16 + l16][((s * 4 + quad) ^ x7) * 8];
                #pragma unroll
                for (int j = 0; j < 4; j++)
                    acc[n][j] = __builtin_amdgcn_mfma_f32_16x16x32_bf16(a[s], b[j], acc[n][j], 0, 0, 0);
            }
            __syncthreads();   // Bs[cur] reads done; prefetch visible next iter
        }
    }

    // epilogue: bias + T residual -> T; full-row LN -> TN
    int rowb = m0 + wid * 16 + quad * 4;
    float sum[4] = {}, sum2[4] = {};
    #pragma unroll
    for (int n = 0; n < 6; n++)
        #pragma unroll
        for (int j = 0; j < 4; j++) {
            int col = n * 64 + j * 16 + l16;
            float bv = proj_b[col];
            #pragma unroll
            for (int r = 0; r < 4; r++) {
                int row = rowb + r;
                float v = acc[n][j][r] + bv;
                if (row < MTOT) v += T[(size_t)row * DIM + col];
                acc[n][j][r] = v;
                sum[r] += v; sum2[r] += v * v;
            }
        }
    float mu[4], rstd[4];
    #pragma unroll
    for (int r = 0; r < 4; r++) {
        float s = sum[r], s2 = sum2[r];
        #pragma unroll
        for (int mk = 1; mk < 16; mk <<= 1) { s += __shfl_xor(s, mk); s2 += __shfl_xor(s2, mk); }
        mu[r] = s * (1.f / DIM);
        rstd[r] = rsqrtf(s2 * (1.f / DIM) - mu[r] * mu[r] + 1e-5f);
    }
    #pragma unroll
    for (int n = 0; n < 6; n++)
        #pragma unroll
        for (int j = 0; j < 4; j++) {
            int col = n * 64 + j * 16 + l16;
            float w = ln2w[col], bb = ln2b[col];
            #pragma unroll
            for (int r = 0; r < 4; r++) {
                int row = rowb + r;
                if (row >= MTOT) continue;
                float v = acc[n][j][r];
                T[(size_t)row * DIM + col] = v;
                TN[(size_t)row * DIM + col] = (__bf16)((v - mu[r]) * rstd[r] * w + bb);
            }
        }
}

// ---------------------------------------------------------------------------
extern "C" void kernel_launch(void* const* d_in, const int* in_sizes, int n_in,
                              void* d_out, int out_size, void* d_ws, size_t ws_size,
                              hipStream_t stream) {
    const float* x      = (const float*)d_in[0];
    const float* conv_w = (const float*)d_in[1];
    // d_in[2] conv_b cancels in reference
    const float* ln1_w  = (const float*)d_in[3];
    const float* ln1_b  = (const float*)d_in[4];
    const float* qkv_w  = (const float*)d_in[5];
    const float* proj_w = (const float*)d_in[6];
    const float* proj_b = (const float*)d_in[7];
    const float* ln2_w  = (const float*)d_in[8];
    const float* ln2_b  = (const float*)d_in[9];
    const float* fc1_w  = (const float*)d_in[10];
    const float* fc1_b  = (const float*)d_in[11];
    const float* fc2_w  = (const float*)d_in[12];
    const float* fc2_b  = (const float*)d_in[13];
    float* out = (float*)d_out;

    char* p = (char*)d_ws;
    float*  T    = (float*)p;  p += (size_t)MTOT * DIM * 4;          //  8.4 MB
    __bf16* TN   = (__bf16*)p; p += (size_t)MTOT * DIM * 2;          //  4.2 MB
    __bf16* QKV  = (__bf16*)p; p += (size_t)MTOT * 1152 * 2;         // 12.6 MB
    __bf16* VT   = (__bf16*)p; p += (size_t)BATCH * DIM * NTOK * 2;  //  4.2 MB
    __bf16* H    = (__bf16*)p; p += (size_t)MTOT * HIDDEN * 2;       // 16.9 MB
    __bf16* WQ   = (__bf16*)p; p += (size_t)1152 * 384 * 2;
    __bf16* WP   = (__bf16*)p; p += (size_t)384 * 384 * 2;
    __bf16* W1   = (__bf16*)p; p += (size_t)1536 * 384 * 2;
    __bf16* W2   = (__bf16*)p; p += (size_t)384 * 1536 * 2;
    float*  LP   = (float*)p;  p += (size_t)KSPLIT * 12 * NTOK * 4;
    float*  OP   = (float*)p;  p += (size_t)KSPLIT * MTOT * DIM * 4; // 25.3 MB

    // 1. conv positional embedding + residual (fp32 trunk) + weight cvt
    k_conv<<<8448 + 1728, 256, 0, stream>>>(
        x, conv_w, T, qkv_w, proj_w, fc1_w, fc2_w, WQ, WP, W1, W2);
    // 2. LN1 -> bf16
    k_ln1<<<MTOT / 4, 256, 0, stream>>>(T, TN, ln1_w, ln1_b);
    // 3. QKV gemm (128x128): Q (pre-scaled), K rows bf16; V -> VT transposed
    k_qkv<<<dim3(9, 43), 256, 0, stream>>>(TN, WQ, QKV, VT, MTOT, 1152, 384);
    // 4. attention split-K partials
    k_attn<<<dim3(NQT, 12, KSPLIT), 256, 0, stream>>>(QKV, VT, OP, LP);
    // 5. fused combine + proj + resid + LN2 -> T, TN
    k_projln<<<(MTOT + 63) / 64, 256, 0, stream>>>(
        OP, LP, WP, proj_b, ln2_w, ln2_b, T, TN);
    // 6. H = gelu(TN @ fc1_w^T + fc1_b) bf16 (128x128)
    k_fc1<<<dim3(12, 43), 256, 0, stream>>>(TN, W1, fc1_b, H, MTOT, 1536, 384);
    // 7. out[b,c,n] = T + H @ fc2_w^T + fc2_b (64x64, transposed store)
    k_fc2<<<dim3(6, 86), 256, 0, stream>>>(H, W2, fc2_b, T, out, MTOT, 384, 1536);
}

// Round 12
// 249.610 us; speedup vs baseline: 1.2575x; 1.2575x over previous
//
#include <hip/hip_runtime.h>
#include <hip/hip_bf16.h>
#include <math.h>

#define DIM 384
#define HEADS 6
#define HIDDEN 1536
#define NTOK 2744   // 14*14*14
#define BATCH 2
#define MTOT (BATCH * NTOK)   // 5488
#define KSPLIT 3
#define NQT 22      // ceil(2744/128)
#define CEXP 0.18033688f   // (1/8) * log2(e)

typedef __bf16 bf16x8 __attribute__((ext_vector_type(8)));
typedef __bf16 bf16x4 __attribute__((ext_vector_type(4)));
typedef float  f32x4  __attribute__((ext_vector_type(4)));

#define F_GELU  1
#define F_RESID 2
#define F_BF16  4
#define F_QKV   8
#define F_TRANS 16

// async global->LDS, 16B per lane; LDS dest = uniform base + lane*16
__device__ __forceinline__ void gll16(const void* g, void* l) {
    __builtin_amdgcn_global_load_lds(
        (const __attribute__((address_space(1))) unsigned int*)g,
        (__attribute__((address_space(3))) unsigned int*)l, 16, 0, 0);
}

// ---------------------------------------------------------------------------
// k_conv: fused depthwise conv3d (+residual, NCDHW -> t[token,C] fp32)
// and weight fp32->bf16 conversion (tail blocks).
// ---------------------------------------------------------------------------
__global__ void k_conv(const float* __restrict__ x, const float* __restrict__ cw,
                       float* __restrict__ t,
                       const float* __restrict__ w0, const float* __restrict__ w1,
                       const float* __restrict__ w2, const float* __restrict__ w3,
                       __bf16* o0, __bf16* o1, __bf16* o2, __bf16* o3) {
    int bid = blockIdx.x;
    if (bid >= 8448) {   // ---- weight conversion ----
        int i = (bid - 8448) * 256 + threadIdx.x;   // float4 index
        const float* s; __bf16* d; int off;
        if (i < 110592)      { s = w0; d = o0; off = i; }
        else if (i < 147456) { s = w1; d = o1; off = i - 110592; }
        else if (i < 294912) { s = w2; d = o2; off = i - 147456; }
        else                 { s = w3; d = o3; off = i - 294912; }
        float4 v = ((const float4*)s)[off];
        bf16x4 bb = { (__bf16)v.x, (__bf16)v.y, (__bf16)v.z, (__bf16)v.w };
        *(bf16x4*)(d + (size_t)off * 4) = bb;
        return;
    }
    int nb = bid % 11, rest = bid / 11;
    int c = rest % 384, b = rest / 384;
    int n = nb * 256 + threadIdx.x;
    if (n >= NTOK) return;
    int d = n / 196, r = n % 196, h = r / 14, w = r % 14;
    const float* xp = x + ((size_t)b * DIM + c) * NTOK;
    const float* wp = cw + c * 27;
    float acc = xp[n];   // residual (conv_b cancels in reference)
    #pragma unroll
    for (int kd = 0; kd < 3; kd++) {
        int dd = d + kd - 1;
        if (dd < 0 || dd >= 14) continue;
        #pragma unroll
        for (int kh = 0; kh < 3; kh++) {
            int hh = h + kh - 1;
            if (hh < 0 || hh >= 14) continue;
            #pragma unroll
            for (int kw = 0; kw < 3; kw++) {
                int ww = w + kw - 1;
                if (ww < 0 || ww >= 14) continue;
                acc += wp[kd * 9 + kh * 3 + kw] * xp[(dd * 14 + hh) * 14 + ww];
            }
        }
    }
    t[((size_t)(b * NTOK + n)) * DIM + c] = acc;
}

// ---------------------------------------------------------------------------
// k_ln1 / k_ln2: LayerNorm fp32 in -> bf16 out. One wave per token.
// ---------------------------------------------------------------------------
__device__ __forceinline__ void ln_body(const float* __restrict__ in,
                                        __bf16* __restrict__ out,
                                        const float* __restrict__ w,
                                        const float* __restrict__ b) {
    int wid = threadIdx.x >> 6, lane = threadIdx.x & 63;
    int token = blockIdx.x * 4 + wid;
    const float* row = in + (size_t)token * DIM;
    float v[6], s = 0.f, s2 = 0.f;
    #pragma unroll
    for (int i = 0; i < 6; i++) {
        v[i] = row[lane + 64 * i];
        s += v[i]; s2 += v[i] * v[i];
    }
    #pragma unroll
    for (int m = 1; m < 64; m <<= 1) { s += __shfl_xor(s, m); s2 += __shfl_xor(s2, m); }
    float mu = s * (1.f / DIM);
    float rstd = rsqrtf(s2 * (1.f / DIM) - mu * mu + 1e-5f);
    __bf16* orow = out + (size_t)token * DIM;
    #pragma unroll
    for (int i = 0; i < 6; i++) {
        int c = lane + 64 * i;
        orow[c] = (__bf16)((v[i] - mu) * rstd * w[c] + b[c]);
    }
}
__global__ void k_ln1(const float* in, __bf16* out, const float* w, const float* b) {
    ln_body(in, out, w, b);
}
__global__ void k_ln2(const float* in, __bf16* out, const float* w, const float* b) {
    ln_body(in, out, w, b);
}

// ---------------------------------------------------------------------------
// gemm 128x64x64, SINGLE-buffered (24 KB LDS -> ~5-6 blocks/CU; cross-block
// wave overlap replaces intra-block prefetch — R10 attn proved this wins at
// short K). XOR chunk swizzle for bank-optimal b128 frag reads.
// ---------------------------------------------------------------------------
__device__ __forceinline__ void gemm12864_body(
    const __bf16* __restrict__ A, const __bf16* __restrict__ B,
    const float* __restrict__ bias, void* __restrict__ out,
    __bf16* __restrict__ vt_out, int M, int N, int K, int flags) {
    __shared__ __bf16 As[128][64];   // 16 KB
    __shared__ __bf16 Bs[64][64];    //  8 KB
    int tid = threadIdx.x, lane = tid & 63, wid = tid >> 6;
    int quad = lane >> 4, l16 = lane & 15;
    int wm = wid & 1, wn = wid >> 1;
    int m0 = blockIdx.y * 128, n0 = blockIdx.x * 64;
    int x7 = l16 & 7;

    auto stage = [&](int k0) {
        #pragma unroll
        for (int i = 0; i < 4; i++) {
            int c = i * 256 + tid;
            int row = c >> 3, cc = (c & 7) ^ (row & 7);
            int gm = m0 + row; if (gm > M - 1) gm = M - 1;
            gll16(A + (size_t)gm * K + k0 + cc * 8, &As[0][0] + (size_t)c * 8);
        }
        #pragma unroll
        for (int i = 0; i < 2; i++) {
            int c = i * 256 + tid;
            int row = c >> 3, cc = (c & 7) ^ (row & 7);
            gll16(B + (size_t)(n0 + row) * K + k0 + cc * 8, &Bs[0][0] + (size_t)c * 8);
        }
    };

    f32x4 acc[4][2] = {};
    int nk = K >> 6;
    for (int ki = 0; ki < nk; ki++) {
        if (ki) __syncthreads();   // prior tile reads done
        stage(ki << 6);
        __syncthreads();           // staging visible
        #pragma unroll
        for (int s = 0; s < 2; s++) {
            bf16x8 a[4], b[2];
            #pragma unroll
            for (int i = 0; i < 4; i++)
                a[i] = *(bf16x8*)&As[wm * 64 + i * 16 + l16][(((s * 4 + quad) ^ x7)) * 8];
            #pragma unroll
            for (int j = 0; j < 2; j++)
                b[j] = *(bf16x8*)&Bs[wn * 32 + j * 16 + l16][(((s * 4 + quad) ^ x7)) * 8];
            #pragma unroll
            for (int i = 0; i < 4; i++)
                #pragma unroll
                for (int j = 0; j < 2; j++)
                    acc[i][j] = __builtin_amdgcn_mfma_f32_16x16x32_bf16(a[i], b[j], acc[i][j], 0, 0, 0);
        }
    }

    int colb = n0 + wn * 32;
    #pragma unroll
    for (int j = 0; j < 2; j++) {
        int col = colb + j * 16 + l16;
        float bv = bias ? bias[col] : 0.f;
        #pragma unroll
        for (int i = 0; i < 4; i++) {
            int row0 = m0 + wm * 64 + i * 16 + quad * 4;
            if (row0 >= M) continue;
            float v4[4];
            #pragma unroll
            for (int r = 0; r < 4; r++) {
                float v = acc[i][j][r] + bv;
                if (flags & F_GELU) v = 0.5f * v * (1.f + erff(v * 0.70710678f));
                if ((flags & F_QKV) && col < 384) v *= CEXP;   // pre-scale Q
                v4[r] = v;
            }
            if ((flags & F_QKV) && col >= 768) {
                int b2 = row0 / NTOK, n2 = row0 - b2 * NTOK;
                bf16x4 pk = { (__bf16)v4[0], (__bf16)v4[1], (__bf16)v4[2], (__bf16)v4[3] };
                *(bf16x4*)(vt_out + ((size_t)(b2 * DIM + (col - 768))) * NTOK + n2) = pk;
            } else {
                #pragma unroll
                for (int r = 0; r < 4; r++)
                    ((__bf16*)out)[(size_t)(row0 + r) * N + col] = (__bf16)v4[r];
            }
        }
    }
}
__global__ __launch_bounds__(256) void k_qkv(const __bf16* A, const __bf16* B,
        void* out, __bf16* vt_out, int M, int N, int K) {
    gemm12864_body(A, B, nullptr, out, vt_out, M, N, K, F_QKV);
}
__global__ __launch_bounds__(256) void k_fc1(const __bf16* A, const __bf16* B,
        const float* bias, void* out, int M, int N, int K) {
    gemm12864_body(A, B, bias, out, nullptr, M, N, K, F_GELU | F_BF16);
}

// ---------------------------------------------------------------------------
// gemm 64x64x64, SINGLE-buffered (16 KB LDS -> ~6 blocks/CU), proj / fc2.
// ---------------------------------------------------------------------------
__device__ __forceinline__ void gemm64_body(
    const __bf16* __restrict__ A, const __bf16* __restrict__ B,
    const float* __restrict__ bias, const float* __restrict__ resid,
    void* __restrict__ out, int M, int N, int K, int flags) {
    __shared__ __bf16 As[64][64];   // 8 KB
    __shared__ __bf16 Bs[64][64];   // 8 KB
    int tid = threadIdx.x, lane = tid & 63, wid = tid >> 6;
    int quad = lane >> 4, l16 = lane & 15;
    int wm = wid & 1, wn = wid >> 1;
    int m0 = blockIdx.y * 64, n0 = blockIdx.x * 64;
    int x7 = l16 & 7;

    auto stage = [&](int k0) {
        #pragma unroll
        for (int i = 0; i < 2; i++) {
            int c = i * 256 + tid;
            int row = c >> 3, cc = (c & 7) ^ (row & 7);
            int gm = m0 + row; if (gm > M - 1) gm = M - 1;
            gll16(A + (size_t)gm * K + k0 + cc * 8, &As[0][0] + (size_t)c * 8);
        }
        #pragma unroll
        for (int i = 0; i < 2; i++) {
            int c = i * 256 + tid;
            int row = c >> 3, cc = (c & 7) ^ (row & 7);
            gll16(B + (size_t)(n0 + row) * K + k0 + cc * 8, &Bs[0][0] + (size_t)c * 8);
        }
    };

    f32x4 acc[2][2] = {};
    int nk = K >> 6;
    for (int ki = 0; ki < nk; ki++) {
        if (ki) __syncthreads();
        stage(ki << 6);
        __syncthreads();
        #pragma unroll
        for (int s = 0; s < 2; s++) {
            bf16x8 a[2], b[2];
            #pragma unroll
            for (int i = 0; i < 2; i++)
                a[i] = *(bf16x8*)&As[wm * 32 + i * 16 + l16][(((s * 4 + quad) ^ x7)) * 8];
            #pragma unroll
            for (int j = 0; j < 2; j++)
                b[j] = *(bf16x8*)&Bs[wn * 32 + j * 16 + l16][(((s * 4 + quad) ^ x7)) * 8];
            #pragma unroll
            for (int i = 0; i < 2; i++)
                #pragma unroll
                for (int j = 0; j < 2; j++)
                    acc[i][j] = __builtin_amdgcn_mfma_f32_16x16x32_bf16(a[i], b[j], acc[i][j], 0, 0, 0);
        }
    }

    #pragma unroll
    for (int j = 0; j < 2; j++) {
        int col = n0 + wn * 32 + j * 16 + l16;
        float bv = bias ? bias[col] : 0.f;
        #pragma unroll
        for (int i = 0; i < 2; i++) {
            int row0 = m0 + wm * 32 + i * 16 + quad * 4;
            if (row0 >= M) continue;
            float v4[4];
            #pragma unroll
            for (int r = 0; r < 4; r++) {
                float v = acc[i][j][r] + bv;
                if (flags & F_RESID) v += resid[(size_t)(row0 + r) * N + col];
                v4[r] = v;
            }
            if (flags & F_TRANS) {
                int b2 = row0 / NTOK, n2 = row0 - b2 * NTOK;
                float4 pk = { v4[0], v4[1], v4[2], v4[3] };
                *(float4*)((float*)out + ((size_t)(b2 * N + col)) * NTOK + n2) = pk;
            } else {
                #pragma unroll
                for (int r = 0; r < 4; r++)
                    ((float*)out)[(size_t)(row0 + r) * N + col] = v4[r];
            }
        }
    }
}
__global__ __launch_bounds__(256) void k_proj(const __bf16* A, const __bf16* B,
        const float* bias, const float* resid, void* out, int M, int N, int K) {
    gemm64_body(A, B, bias, resid, out, M, N, K, F_RESID);
}
__global__ __launch_bounds__(256) void k_fc2(const __bf16* A, const __bf16* B,
        const float* bias, const float* resid, void* out, int M, int N, int K) {
    gemm64_body(A, B, bias, resid, out, M, N, K, F_RESID | F_TRANS);
}

// ---------------------------------------------------------------------------
// k_attn: bf16 MFMA flash attention (R10-proven): 4 waves x 32 queries,
// single-buffered K/V (34.8 KB LDS -> 4 blocks/CU), Ps padded stride 72
// overlays Q staging, Q pre-scaled by CEXP, unnormalized exp + split-K.
// ---------------------------------------------------------------------------
__global__ __launch_bounds__(256) void k_attn(const __bf16* __restrict__ qkv,
                                              const __bf16* __restrict__ vt,
                                              float* __restrict__ opart,
                                              float* __restrict__ lpart) {
    __shared__ __align__(16) char smemQP[128 * 72 * 2];   // 18 KB: Q stage, then Ps
    __shared__ __bf16 Ks[64][64];    // 8 KB
    __shared__ __bf16 Vt[64][64];    // 8 KB
    __bf16 (*Qs)[64] = (__bf16(*)[64])smemQP;
    __bf16 (*Ps)[72] = (__bf16(*)[72])smemQP;

    int tid = threadIdx.x, lane = tid & 63, wid = tid >> 6;
    int quad = lane >> 4, l16 = lane & 15;
    int q0 = blockIdx.x * 128;
    int bh = blockIdx.y;
    int ks = blockIdx.z;
    int b = bh / HEADS, h = bh % HEADS;
    int x7 = l16 & 7;

    auto stageKV = [&](int k0) {
        #pragma unroll
        for (int i = 0; i < 2; i++) {
            int c = i * 256 + tid;
            int row = c >> 3, cc = (c & 7) ^ (row & 7);
            int gk = k0 + row; if (gk > NTOK - 1) gk = NTOK - 1;
            gll16(qkv + ((size_t)(b * NTOK + gk)) * 1152 + 384 + h * 64 + cc * 8,
                  &Ks[0][0] + (size_t)c * 8);
            gll16(vt + ((size_t)(bh * 64 + row)) * NTOK + k0 + cc * 8,
                  &Vt[0][0] + (size_t)c * 8);
        }
    };

    int kt0 = (43 * ks) / KSPLIT, kt1 = (43 * (ks + 1)) / KSPLIT;

    #pragma unroll
    for (int i = 0; i < 4; i++) {
        int c = i * 256 + tid;
        int row = c >> 3, cc = (c & 7) ^ (row & 7);
        int gq = q0 + row; if (gq > NTOK - 1) gq = NTOK - 1;
        gll16(qkv + ((size_t)(b * NTOK + gq)) * 1152 + h * 64 + cc * 8,
              &Qs[0][0] + (size_t)c * 8);
    }
    stageKV(kt0 * 64);
    __syncthreads();

    bf16x8 aq[2][2];
    #pragma unroll
    for (int qt = 0; qt < 2; qt++)
        #pragma unroll
        for (int s = 0; s < 2; s++)
            aq[qt][s] = *(bf16x8*)&Qs[wid * 32 + qt * 16 + l16][((s * 4 + quad) ^ x7) * 8];
    __syncthreads();   // Qs -> Ps overlay handoff

    f32x4 oacc[2][4] = {};
    float l_part[2][4] = {};
    __bf16* pwr = &Ps[wid * 32 + quad * 4][l16];
    const __bf16* prd = &Ps[wid * 32 + l16][0];

    for (int kt = kt0; kt < kt1; kt++) {
        if (kt > kt0) {
            __syncthreads();
            stageKV(kt * 64);
            __syncthreads();
        }
        int k0 = kt * 64;

        f32x4 s[2][4];
        #pragma unroll
        for (int t = 0; t < 4; t++) {
            bf16x8 bk0 = *(bf16x8*)&Ks[t * 16 + l16][((quad) ^ x7) * 8];
            bf16x8 bk1 = *(bf16x8*)&Ks[t * 16 + l16][((4 + quad) ^ x7) * 8];
            #pragma unroll
            for (int qt = 0; qt < 2; qt++) {
                f32x4 z = {0.f, 0.f, 0.f, 0.f};
                z = __builtin_amdgcn_mfma_f32_16x16x32_bf16(aq[qt][0], bk0, z, 0, 0, 0);
                s[qt][t] = __builtin_amdgcn_mfma_f32_16x16x32_bf16(aq[qt][1], bk1, z, 0, 0, 0);
            }
        }
        if (k0 + 64 > NTOK) {
            #pragma unroll
            for (int t = 0; t < 4; t++)
                if (k0 + t * 16 + l16 >= NTOK)
                    #pragma unroll
                    for (int qt = 0; qt < 2; qt++) {
                        s[qt][t][0] = -1e30f; s[qt][t][1] = -1e30f;
                        s[qt][t][2] = -1e30f; s[qt][t][3] = -1e30f;
                    }
        }
        #pragma unroll
        for (int qt = 0; qt < 2; qt++)
            #pragma unroll
            for (int t = 0; t < 4; t++)
                #pragma unroll
                for (int r = 0; r < 4; r++) {
                    float e = exp2f(s[qt][t][r]);   // scale folded into Q
                    l_part[qt][r] += e;
                    pwr[(qt * 16 + r) * 72 + t * 16] = (__bf16)e;
                }
        bf16x8 ap[2][2];
        #pragma unroll
        for (int qt = 0; qt < 2; qt++)
            #pragma unroll
            for (int sx = 0; sx < 2; sx++)
                ap[qt][sx] = *(bf16x8*)(prd + qt * 16 * 72 + sx * 32 + quad * 8);
        #pragma unroll
        for (int t = 0; t < 4; t++) {
            bf16x8 bv0 = *(bf16x8*)&Vt[t * 16 + l16][((quad) ^ x7) * 8];
            bf16x8 bv1 = *(bf16x8*)&Vt[t * 16 + l16][((4 + quad) ^ x7) * 8];
            #pragma unroll
            for (int qt = 0; qt < 2; qt++) {
                oacc[qt][t] = __builtin_amdgcn_mfma_f32_16x16x32_bf16(ap[qt][0], bv0, oacc[qt][t], 0, 0, 0);
                oacc[qt][t] = __builtin_amdgcn_mfma_f32_16x16x32_bf16(ap[qt][1], bv1, oacc[qt][t], 0, 0, 0);
            }
        }
    }

    #pragma unroll
    for (int qt = 0; qt < 2; qt++)
        #pragma unroll
        for (int r = 0; r < 4; r++) {
            int gq = q0 + wid * 32 + qt * 16 + quad * 4 + r;
            if (gq >= NTOK) continue;
            float l = l_part[qt][r];
            #pragma unroll
            for (int mk = 1; mk < 16; mk <<= 1) l += __shfl_xor(l, mk);
            if (l16 == 0) lpart[((size_t)ks * 12 + bh) * NTOK + gq] = l;
            float* op = opart + ((size_t)ks * MTOT + (size_t)b * NTOK + gq) * DIM + h * 64;
            #pragma unroll
            for (int t = 0; t < 4; t++) op[t * 16 + l16] = oacc[qt][t][r];
        }
}

// ---------------------------------------------------------------------------
// k_comb: combine split-K partials -> O bf16.
// ---------------------------------------------------------------------------
__global__ void k_comb(const float* __restrict__ opart,
                       const float* __restrict__ lpart,
                       __bf16* __restrict__ o) {
    int idx = blockIdx.x * 256 + threadIdx.x;   // MTOT*96 total
    int token = idx / 96, rem = idx - token * 96;
    int c = rem * 4, h = c >> 6;
    int b2 = token / NTOK, n = token - b2 * NTOK;
    int bh = b2 * HEADS + h;
    f32x4 acc = {0.f, 0.f, 0.f, 0.f};
    float l = 0.f;
    #pragma unroll
    for (int ks = 0; ks < KSPLIT; ks++) {
        f32x4 p = *(const f32x4*)&opart[((size_t)ks * MTOT + token) * DIM + c];
        acc[0] += p[0]; acc[1] += p[1]; acc[2] += p[2]; acc[3] += p[3];
        l += lpart[((size_t)ks * 12 + bh) * NTOK + n];
    }
    float inv = 1.f / l;
    bf16x4 ov = { (__bf16)(acc[0] * inv), (__bf16)(acc[1] * inv),
                  (__bf16)(acc[2] * inv), (__bf16)(acc[3] * inv) };
    *(bf16x4*)(o + (size_t)token * DIM + c) = ov;
}

// ---------------------------------------------------------------------------
extern "C" void kernel_launch(void* const* d_in, const int* in_sizes, int n_in,
                              void* d_out, int out_size, void* d_ws, size_t ws_size,
                              hipStream_t stream) {
    const float* x      = (const float*)d_in[0];
    const float* conv_w = (const float*)d_in[1];
    // d_in[2] conv_b cancels in reference
    const float* ln1_w  = (const float*)d_in[3];
    const float* ln1_b  = (const float*)d_in[4];
    const float* qkv_w  = (const float*)d_in[5];
    const float* proj_w = (const float*)d_in[6];
    const float* proj_b = (const float*)d_in[7];
    const float* ln2_w  = (const float*)d_in[8];
    const float* ln2_b  = (const float*)d_in[9];
    const float* fc1_w  = (const float*)d_in[10];
    const float* fc1_b  = (const float*)d_in[11];
    const float* fc2_w  = (const float*)d_in[12];
    const float* fc2_b  = (const float*)d_in[13];
    float* out = (float*)d_out;

    char* p = (char*)d_ws;
    float*  T    = (float*)p;  p += (size_t)MTOT * DIM * 4;          //  8.4 MB
    __bf16* TN   = (__bf16*)p; p += (size_t)MTOT * DIM * 2;          //  4.2 MB
    __bf16* QKV  = (__bf16*)p; p += (size_t)MTOT * 1152 * 2;         // 12.6 MB
    __bf16* VT   = (__bf16*)p; p += (size_t)BATCH * DIM * NTOK * 2;  //  4.2 MB
    __bf16* O    = (__bf16*)p; p += (size_t)MTOT * DIM * 2;          //  4.2 MB
    __bf16* H    = (__bf16*)p; p += (size_t)MTOT * HIDDEN * 2;       // 16.9 MB
    __bf16* WQ   = (__bf16*)p; p += (size_t)1152 * 384 * 2;
    __bf16* WP   = (__bf16*)p; p += (size_t)384 * 384 * 2;
    __bf16* W1   = (__bf16*)p; p += (size_t)1536 * 384 * 2;
    __bf16* W2   = (__bf16*)p; p += (size_t)384 * 1536 * 2;
    float*  LP   = (float*)p;  p += (size_t)KSPLIT * 12 * NTOK * 4;
    float*  OP   = (float*)p;  p += (size_t)KSPLIT * MTOT * DIM * 4; // 25.3 MB

    // 1. conv positional embedding + residual (fp32 trunk) + weight cvt
    k_conv<<<8448 + 1728, 256, 0, stream>>>(
        x, conv_w, T, qkv_w, proj_w, fc1_w, fc2_w, WQ, WP, W1, W2);
    // 2. LN1 -> bf16
    k_ln1<<<MTOT / 4, 256, 0, stream>>>(T, TN, ln1_w, ln1_b);
    // 3. QKV gemm (128x64 single-buffer, grid 774): Q pre-scaled; V -> VT
    k_qkv<<<dim3(18, 43), 256, 0, stream>>>(TN, WQ, QKV, VT, MTOT, 1152, 384);
    // 4. attention split-K partials + combine -> O bf16
    k_attn<<<dim3(NQT, 12, KSPLIT), 256, 0, stream>>>(QKV, VT, OP, LP);
    k_comb<<<(MTOT * 96) / 256, 256, 0, stream>>>(OP, LP, O);
    // 5. T += O @ proj_w^T + proj_b (64x64 single-buffer, grid 516)
    k_proj<<<dim3(6, 86), 256, 0, stream>>>(O, WP, proj_b, T, T, MTOT, 384, 384);
    // 6. LN2 -> bf16
    k_ln2<<<MTOT / 4, 256, 0, stream>>>(T, TN, ln2_w, ln2_b);
    // 7. H = gelu(TN @ fc1_w^T + fc1_b) bf16 (128x64 single-buffer, grid 1032)
    k_fc1<<<dim3(24, 43), 256, 0, stream>>>(TN, W1, fc1_b, H, MTOT, 1536, 384);
    // 8. out[b,c,n] = T + H @ fc2_w^T + fc2_b (64x64 single-buffer)
    k_fc2<<<dim3(6, 86), 256, 0, stream>>>(H, W2, fc2_b, T, out, MTOT, 384, 1536);
}

// Round 13
// 231.159 us; speedup vs baseline: 1.3578x; 1.0798x over previous
//
#include <hip/hip_runtime.h>
#include <hip/hip_bf16.h>
#include <math.h>

#define DIM 384
#define HEADS 6
#define HIDDEN 1536
#define NTOK 2744   // 14*14*14
#define BATCH 2
#define MTOT (BATCH * NTOK)   // 5488
#define KSPLIT 4
#define NQT 22      // ceil(2744/128)
#define CEXP 0.18033688f   // (1/8) * log2(e)

typedef __bf16 bf16x8 __attribute__((ext_vector_type(8)));
typedef __bf16 bf16x4 __attribute__((ext_vector_type(4)));
typedef float  f32x4  __attribute__((ext_vector_type(4)));

#define F_GELU  1
#define F_RESID 2
#define F_BF16  4
#define F_QKV   8
#define F_TRANS 16

// async global->LDS, 16B per lane; LDS dest = uniform base + lane*16
__device__ __forceinline__ void gll16(const void* g, void* l) {
    __builtin_amdgcn_global_load_lds(
        (const __attribute__((address_space(1))) unsigned int*)g,
        (__attribute__((address_space(3))) unsigned int*)l, 16, 0, 0);
}

// ---------------------------------------------------------------------------
// k_conv: depthwise conv3d (+residual) with WRITE-COMBINED output.
// Block = 256 tokens x 16 channels: each thread computes 16 channels of one
// token and writes one aligned 64 B line of T (R12 version wrote 4 B at
// 1536 B stride from 16 different blocks -> massive write amplification).
// Tail blocks (bid >= 528) do weight fp32->bf16 conversion.
// conv grid: 11 token-blocks x 24 ch-blocks x 2 batch = 528.
// ---------------------------------------------------------------------------
__global__ void k_conv(const float* __restrict__ x, const float* __restrict__ cw,
                       float* __restrict__ t,
                       const float* __restrict__ w0, const float* __restrict__ w1,
                       const float* __restrict__ w2, const float* __restrict__ w3,
                       __bf16* o0, __bf16* o1, __bf16* o2, __bf16* o3) {
    int bid = blockIdx.x;
    if (bid >= 528) {   // ---- weight conversion ----
        int i = (bid - 528) * 256 + threadIdx.x;   // float4 index
        const float* s; __bf16* d; int off;
        if (i < 110592)      { s = w0; d = o0; off = i; }
        else if (i < 147456) { s = w1; d = o1; off = i - 110592; }
        else if (i < 294912) { s = w2; d = o2; off = i - 147456; }
        else                 { s = w3; d = o3; off = i - 294912; }
        float4 v = ((const float4*)s)[off];
        bf16x4 bb = { (__bf16)v.x, (__bf16)v.y, (__bf16)v.z, (__bf16)v.w };
        *(bf16x4*)(d + (size_t)off * 4) = bb;
        return;
    }
    int nb = bid % 11, rest = bid / 11;
    int cb = rest % 24, b = rest / 24;
    int c0 = cb * 16;
    int n = nb * 256 + threadIdx.x;
    if (n >= NTOK) return;
    int d = n / 196, r = n % 196, h = r / 14, w = r % 14;
    const float* xb = x + ((size_t)b * DIM + c0) * NTOK;
    float acc[16];
    #pragma unroll
    for (int c = 0; c < 16; c++) acc[c] = xb[(size_t)c * NTOK + n];   // residual
    #pragma unroll
    for (int kd = 0; kd < 3; kd++) {
        int dd = d + kd - 1;
        if (dd < 0 || dd >= 14) continue;
        #pragma unroll
        for (int kh = 0; kh < 3; kh++) {
            int hh = h + kh - 1;
            if (hh < 0 || hh >= 14) continue;
            #pragma unroll
            for (int kw = 0; kw < 3; kw++) {
                int ww = w + kw - 1;
                if (ww < 0 || ww >= 14) continue;
                int np = (dd * 14 + hh) * 14 + ww;
                int tap = kd * 9 + kh * 3 + kw;
                #pragma unroll
                for (int c = 0; c < 16; c++)   // weight idx block-uniform -> s_load
                    acc[c] = fmaf(cw[(c0 + c) * 27 + tap], xb[(size_t)c * NTOK + np], acc[c]);
            }
        }
    }
    float* tp = t + (size_t)(b * NTOK + n) * DIM + c0;   // 64 B aligned line
    #pragma unroll
    for (int c = 0; c < 16; c += 4) {
        float4 v = { acc[c], acc[c + 1], acc[c + 2], acc[c + 3] };
        *(float4*)(tp + c) = v;
    }
}

// ---------------------------------------------------------------------------
// k_ln1 / k_ln2: LayerNorm fp32 in -> bf16 out. One wave per token.
// ---------------------------------------------------------------------------
__device__ __forceinline__ void ln_body(const float* __restrict__ in,
                                        __bf16* __restrict__ out,
                                        const float* __restrict__ w,
                                        const float* __restrict__ b) {
    int wid = threadIdx.x >> 6, lane = threadIdx.x & 63;
    int token = blockIdx.x * 4 + wid;
    const float* row = in + (size_t)token * DIM;
    float v[6], s = 0.f, s2 = 0.f;
    #pragma unroll
    for (int i = 0; i < 6; i++) {
        v[i] = row[lane + 64 * i];
        s += v[i]; s2 += v[i] * v[i];
    }
    #pragma unroll
    for (int m = 1; m < 64; m <<= 1) { s += __shfl_xor(s, m); s2 += __shfl_xor(s2, m); }
    float mu = s * (1.f / DIM);
    float rstd = rsqrtf(s2 * (1.f / DIM) - mu * mu + 1e-5f);
    __bf16* orow = out + (size_t)token * DIM;
    #pragma unroll
    for (int i = 0; i < 6; i++) {
        int c = lane + 64 * i;
        orow[c] = (__bf16)((v[i] - mu) * rstd * w[c] + b[c]);
    }
}
__global__ void k_ln1(const float* in, __bf16* out, const float* w, const float* b) {
    ln_body(in, out, w, b);
}
__global__ void k_ln2(const float* in, __bf16* out, const float* w, const float* b) {
    ln_body(in, out, w, b);
}

// ---------------------------------------------------------------------------
// gemm 128x64x64, SINGLE-buffered (24 KB LDS), XOR chunk swizzle (QKV, FC1).
// ---------------------------------------------------------------------------
__device__ __forceinline__ void gemm12864_body(
    const __bf16* __restrict__ A, const __bf16* __restrict__ B,
    const float* __restrict__ bias, void* __restrict__ out,
    __bf16* __restrict__ vt_out, int M, int N, int K, int flags) {
    __shared__ __bf16 As[128][64];   // 16 KB
    __shared__ __bf16 Bs[64][64];    //  8 KB
    int tid = threadIdx.x, lane = tid & 63, wid = tid >> 6;
    int quad = lane >> 4, l16 = lane & 15;
    int wm = wid & 1, wn = wid >> 1;
    int m0 = blockIdx.y * 128, n0 = blockIdx.x * 64;
    int x7 = l16 & 7;

    auto stage = [&](int k0) {
        #pragma unroll
        for (int i = 0; i < 4; i++) {
            int c = i * 256 + tid;
            int row = c >> 3, cc = (c & 7) ^ (row & 7);
            int gm = m0 + row; if (gm > M - 1) gm = M - 1;
            gll16(A + (size_t)gm * K + k0 + cc * 8, &As[0][0] + (size_t)c * 8);
        }
        #pragma unroll
        for (int i = 0; i < 2; i++) {
            int c = i * 256 + tid;
            int row = c >> 3, cc = (c & 7) ^ (row & 7);
            gll16(B + (size_t)(n0 + row) * K + k0 + cc * 8, &Bs[0][0] + (size_t)c * 8);
        }
    };

    f32x4 acc[4][2] = {};
    int nk = K >> 6;
    for (int ki = 0; ki < nk; ki++) {
        if (ki) __syncthreads();
        stage(ki << 6);
        __syncthreads();
        #pragma unroll
        for (int s = 0; s < 2; s++) {
            bf16x8 a[4], b[2];
            #pragma unroll
            for (int i = 0; i < 4; i++)
                a[i] = *(bf16x8*)&As[wm * 64 + i * 16 + l16][(((s * 4 + quad) ^ x7)) * 8];
            #pragma unroll
            for (int j = 0; j < 2; j++)
                b[j] = *(bf16x8*)&Bs[wn * 32 + j * 16 + l16][(((s * 4 + quad) ^ x7)) * 8];
            #pragma unroll
            for (int i = 0; i < 4; i++)
                #pragma unroll
                for (int j = 0; j < 2; j++)
                    acc[i][j] = __builtin_amdgcn_mfma_f32_16x16x32_bf16(a[i], b[j], acc[i][j], 0, 0, 0);
        }
    }

    int colb = n0 + wn * 32;
    #pragma unroll
    for (int j = 0; j < 2; j++) {
        int col = colb + j * 16 + l16;
        float bv = bias ? bias[col] : 0.f;
        #pragma unroll
        for (int i = 0; i < 4; i++) {
            int row0 = m0 + wm * 64 + i * 16 + quad * 4;
            if (row0 >= M) continue;
            float v4[4];
            #pragma unroll
            for (int r = 0; r < 4; r++) {
                float v = acc[i][j][r] + bv;
                if (flags & F_GELU) v = 0.5f * v * (1.f + erff(v * 0.70710678f));
                if ((flags & F_QKV) && col < 384) v *= CEXP;   // pre-scale Q
                v4[r] = v;
            }
            if ((flags & F_QKV) && col >= 768) {
                int b2 = row0 / NTOK, n2 = row0 - b2 * NTOK;
                bf16x4 pk = { (__bf16)v4[0], (__bf16)v4[1], (__bf16)v4[2], (__bf16)v4[3] };
                *(bf16x4*)(vt_out + ((size_t)(b2 * DIM + (col - 768))) * NTOK + n2) = pk;
            } else {
                #pragma unroll
                for (int r = 0; r < 4; r++)
                    ((__bf16*)out)[(size_t)(row0 + r) * N + col] = (__bf16)v4[r];
            }
        }
    }
}
__global__ __launch_bounds__(256) void k_qkv(const __bf16* A, const __bf16* B,
        void* out, __bf16* vt_out, int M, int N, int K) {
    gemm12864_body(A, B, nullptr, out, vt_out, M, N, K, F_QKV);
}
__global__ __launch_bounds__(256) void k_fc1(const __bf16* A, const __bf16* B,
        const float* bias, void* out, int M, int N, int K) {
    gemm12864_body(A, B, bias, out, nullptr, M, N, K, F_GELU | F_BF16);
}

// ---------------------------------------------------------------------------
// gemm 64x64x64, SINGLE-buffered, proj / fc2. F_TRANS path does an LDS
// transpose (two 32-col halves, [32][68] fp32) so the out[b,c,n] store is
// 256 B-contiguous coalesced (raw lane stores were 16 B at 11 KB stride).
// ---------------------------------------------------------------------------
__device__ __forceinline__ void gemm64_body(
    const __bf16* __restrict__ A, const __bf16* __restrict__ B,
    const float* __restrict__ bias, const float* __restrict__ resid,
    void* __restrict__ out, int M, int N, int K, int flags) {
    __shared__ __align__(16) char sm[17408];   // As 8K @0, Bs 8K @8192; Tt reuse
    __bf16 (*As)[64] = (__bf16(*)[64])sm;
    __bf16 (*Bs)[64] = (__bf16(*)[64])(sm + 8192);
    float* Tt = (float*)sm;                    // [32][68] fp32 = 8704 B
    int tid = threadIdx.x, lane = tid & 63, wid = tid >> 6;
    int quad = lane >> 4, l16 = lane & 15;
    int wm = wid & 1, wn = wid >> 1;
    int m0 = blockIdx.y * 64, n0 = blockIdx.x * 64;
    int x7 = l16 & 7;

    auto stage = [&](int k0) {
        #pragma unroll
        for (int i = 0; i < 2; i++) {
            int c = i * 256 + tid;
            int row = c >> 3, cc = (c & 7) ^ (row & 7);
            int gm = m0 + row; if (gm > M - 1) gm = M - 1;
            gll16(A + (size_t)gm * K + k0 + cc * 8, &As[0][0] + (size_t)c * 8);
        }
        #pragma unroll
        for (int i = 0; i < 2; i++) {
            int c = i * 256 + tid;
            int row = c >> 3, cc = (c & 7) ^ (row & 7);
            gll16(B + (size_t)(n0 + row) * K + k0 + cc * 8, &Bs[0][0] + (size_t)c * 8);
        }
    };

    f32x4 acc[2][2] = {};
    int nk = K >> 6;
    for (int ki = 0; ki < nk; ki++) {
        if (ki) __syncthreads();
        stage(ki << 6);
        __syncthreads();
        #pragma unroll
        for (int s = 0; s < 2; s++) {
            bf16x8 a[2], b[2];
            #pragma unroll
            for (int i = 0; i < 2; i++)
                a[i] = *(bf16x8*)&As[wm * 32 + i * 16 + l16][(((s * 4 + quad) ^ x7)) * 8];
            #pragma unroll
            for (int j = 0; j < 2; j++)
                b[j] = *(bf16x8*)&Bs[wn * 32 + j * 16 + l16][(((s * 4 + quad) ^ x7)) * 8];
            #pragma unroll
            for (int i = 0; i < 2; i++)
                #pragma unroll
                for (int j = 0; j < 2; j++)
                    acc[i][j] = __builtin_amdgcn_mfma_f32_16x16x32_bf16(a[i], b[j], acc[i][j], 0, 0, 0);
        }
    }

    if (flags & F_TRANS) {
        // coalesced transposed store via LDS, two 32-col halves
        #pragma unroll
        for (int half = 0; half < 2; half++) {
            __syncthreads();   // staging (or prior half) reads done
            if (wn == half) {
                #pragma unroll
                for (int j = 0; j < 2; j++) {
                    int colL = j * 16 + l16;                 // 0..31 in half
                    int col = n0 + half * 32 + colL;
                    float bv = bias[col];
                    #pragma unroll
                    for (int i = 0; i < 2; i++) {
                        int rowL = wm * 32 + i * 16 + quad * 4;
                        float v4[4];
                        #pragma unroll
                        for (int r = 0; r < 4; r++) {
                            int rr = m0 + rowL + r; if (rr > M - 1) rr = M - 1;
                            v4[r] = acc[i][j][r] + bv + resid[(size_t)rr * N + col];
                        }
                        float4 pk = { v4[0], v4[1], v4[2], v4[3] };
                        *(float4*)&Tt[colL * 68 + rowL] = pk;
                    }
                }
            }
            __syncthreads();
            int c = tid >> 3, no = (tid & 7) * 8;
            int col = n0 + half * 32 + c;
            #pragma unroll
            for (int q2 = 0; q2 < 2; q2++) {
                int nn = no + q2 * 4;
                int row = m0 + nn;
                if (row >= M) continue;
                int b2 = row / NTOK, n2 = row - b2 * NTOK;
                float4 v = *(float4*)&Tt[c * 68 + nn];
                *(float4*)((float*)out + ((size_t)(b2 * N + col)) * NTOK + n2) = v;
            }
        }
        return;
    }

    #pragma unroll
    for (int j = 0; j < 2; j++) {
        int col = n0 + wn * 32 + j * 16 + l16;
        float bv = bias ? bias[col] : 0.f;
        #pragma unroll
        for (int i = 0; i < 2; i++) {
            int row0 = m0 + wm * 32 + i * 16 + quad * 4;
            if (row0 >= M) continue;
            #pragma unroll
            for (int r = 0; r < 4; r++) {
                float v = acc[i][j][r] + bv;
                if (flags & F_RESID) v += resid[(size_t)(row0 + r) * N + col];
                ((float*)out)[(size_t)(row0 + r) * N + col] = v;
            }
        }
    }
}
__global__ __launch_bounds__(256) void k_proj(const __bf16* A, const __bf16* B,
        const float* bias, const float* resid, void* out, int M, int N, int K) {
    gemm64_body(A, B, bias, resid, out, M, N, K, F_RESID);
}
__global__ __launch_bounds__(256) void k_fc2(const __bf16* A, const __bf16* B,
        const float* bias, const float* resid, void* out, int M, int N, int K) {
    gemm64_body(A, B, bias, resid, out, M, N, K, F_RESID | F_TRANS);
}

// ---------------------------------------------------------------------------
// k_attn: bf16 MFMA flash attention (R10/R12-proven core): 4 waves x 32
// queries, single-buffered K/V (34.8 KB -> 4 blocks/CU), Ps stride 72
// overlays Q staging, Q pre-scaled by CEXP, unnormalized exp.
// KSPLIT=4 (grid 1056 -> 4 resident blocks/CU); partials stored bf16.
// ---------------------------------------------------------------------------
__global__ __launch_bounds__(256) void k_attn(const __bf16* __restrict__ qkv,
                                              const __bf16* __restrict__ vt,
                                              __bf16* __restrict__ opart,
                                              float* __restrict__ lpart) {
    __shared__ __align__(16) char smemQP[128 * 72 * 2];   // 18 KB: Q stage, then Ps
    __shared__ __bf16 Ks[64][64];    // 8 KB
    __shared__ __bf16 Vt[64][64];    // 8 KB
    __bf16 (*Qs)[64] = (__bf16(*)[64])smemQP;
    __bf16 (*Ps)[72] = (__bf16(*)[72])smemQP;

    int tid = threadIdx.x, lane = tid & 63, wid = tid >> 6;
    int quad = lane >> 4, l16 = lane & 15;
    int q0 = blockIdx.x * 128;
    int bh = blockIdx.y;
    int ks = blockIdx.z;
    int b = bh / HEADS, h = bh % HEADS;
    int x7 = l16 & 7;

    auto stageKV = [&](int k0) {
        #pragma unroll
        for (int i = 0; i < 2; i++) {
            int c = i * 256 + tid;
            int row = c >> 3, cc = (c & 7) ^ (row & 7);
            int gk = k0 + row; if (gk > NTOK - 1) gk = NTOK - 1;
            gll16(qkv + ((size_t)(b * NTOK + gk)) * 1152 + 384 + h * 64 + cc * 8,
                  &Ks[0][0] + (size_t)c * 8);
            gll16(vt + ((size_t)(bh * 64 + row)) * NTOK + k0 + cc * 8,
                  &Vt[0][0] + (size_t)c * 8);
        }
    };

    int kt0 = (43 * ks) / KSPLIT, kt1 = (43 * (ks + 1)) / KSPLIT;

    #pragma unroll
    for (int i = 0; i < 4; i++) {
        int c = i * 256 + tid;
        int row = c >> 3, cc = (c & 7) ^ (row & 7);
        int gq = q0 + row; if (gq > NTOK - 1) gq = NTOK - 1;
        gll16(qkv + ((size_t)(b * NTOK + gq)) * 1152 + h * 64 + cc * 8,
              &Qs[0][0] + (size_t)c * 8);
    }
    stageKV(kt0 * 64);
    __syncthreads();

    bf16x8 aq[2][2];
    #pragma unroll
    for (int qt = 0; qt < 2; qt++)
        #pragma unroll
        for (int s = 0; s < 2; s++)
            aq[qt][s] = *(bf16x8*)&Qs[wid * 32 + qt * 16 + l16][((s * 4 + quad) ^ x7) * 8];
    __syncthreads();   // Qs -> Ps overlay handoff

    f32x4 oacc[2][4] = {};
    float l_part[2][4] = {};
    __bf16* pwr = &Ps[wid * 32 + quad * 4][l16];
    const __bf16* prd = &Ps[wid * 32 + l16][0];

    for (int kt = kt0; kt < kt1; kt++) {
        if (kt > kt0) {
            __syncthreads();
            stageKV(kt * 64);
            __syncthreads();
        }
        int k0 = kt * 64;

        f32x4 s[2][4];
        #pragma unroll
        for (int t = 0; t < 4; t++) {
            bf16x8 bk0 = *(bf16x8*)&Ks[t * 16 + l16][((quad) ^ x7) * 8];
            bf16x8 bk1 = *(bf16x8*)&Ks[t * 16 + l16][((4 + quad) ^ x7) * 8];
            #pragma unroll
            for (int qt = 0; qt < 2; qt++) {
                f32x4 z = {0.f, 0.f, 0.f, 0.f};
                z = __builtin_amdgcn_mfma_f32_16x16x32_bf16(aq[qt][0], bk0, z, 0, 0, 0);
                s[qt][t] = __builtin_amdgcn_mfma_f32_16x16x32_bf16(aq[qt][1], bk1, z, 0, 0, 0);
            }
        }
        if (k0 + 64 > NTOK) {
            #pragma unroll
            for (int t = 0; t < 4; t++)
                if (k0 + t * 16 + l16 >= NTOK)
                    #pragma unroll
                    for (int qt = 0; qt < 2; qt++) {
                        s[qt][t][0] = -1e30f; s[qt][t][1] = -1e30f;
                        s[qt][t][2] = -1e30f; s[qt][t][3] = -1e30f;
                    }
        }
        #pragma unroll
        for (int qt = 0; qt < 2; qt++)
            #pragma unroll
            for (int t = 0; t < 4; t++)
                #pragma unroll
                for (int r = 0; r < 4; r++) {
                    float e = exp2f(s[qt][t][r]);   // scale folded into Q
                    l_part[qt][r] += e;
                    pwr[(qt * 16 + r) * 72 + t * 16] = (__bf16)e;
                }
        bf16x8 ap[2][2];
        #pragma unroll
        for (int qt = 0; qt < 2; qt++)
            #pragma unroll
            for (int sx = 0; sx < 2; sx++)
                ap[qt][sx] = *(bf16x8*)(prd + qt * 16 * 72 + sx * 32 + quad * 8);
        #pragma unroll
        for (int t = 0; t < 4; t++) {
            bf16x8 bv0 = *(bf16x8*)&Vt[t * 16 + l16][((quad) ^ x7) * 8];
            bf16x8 bv1 = *(bf16x8*)&Vt[t * 16 + l16][((4 + quad) ^ x7) * 8];
            #pragma unroll
            for (int qt = 0; qt < 2; qt++) {
                oacc[qt][t] = __builtin_amdgcn_mfma_f32_16x16x32_bf16(ap[qt][0], bv0, oacc[qt][t], 0, 0, 0);
                oacc[qt][t] = __builtin_amdgcn_mfma_f32_16x16x32_bf16(ap[qt][1], bv1, oacc[qt][t], 0, 0, 0);
            }
        }
    }

    // store unnormalized partials (bf16)
    #pragma unroll
    for (int qt = 0; qt < 2; qt++)
        #pragma unroll
        for (int r = 0; r < 4; r++) {
            int gq = q0 + wid * 32 + qt * 16 + quad * 4 + r;
            if (gq >= NTOK) continue;
            float l = l_part[qt][r];
            #pragma unroll
            for (int mk = 1; mk < 16; mk <<= 1) l += __shfl_xor(l, mk);
            if (l16 == 0) lpart[((size_t)ks * 12 + bh) * NTOK + gq] = l;
            __bf16* op = opart + ((size_t)ks * MTOT + (size_t)b * NTOK + gq) * DIM + h * 64;
            #pragma unroll
            for (int t = 0; t < 4; t++) op[t * 16 + l16] = (__bf16)oacc[qt][t][r];
        }
}

// ---------------------------------------------------------------------------
// k_comb: combine split-K partials (bf16) -> O bf16.
// ---------------------------------------------------------------------------
__global__ void k_comb(const __bf16* __restrict__ opart,
                       const float* __restrict__ lpart,
                       __bf16* __restrict__ o) {
    int idx = blockIdx.x * 256 + threadIdx.x;   // MTOT*96 total
    int token = idx / 96, rem = idx - token * 96;
    int c = rem * 4, h = c >> 6;
    int b2 = token / NTOK, n = token - b2 * NTOK;
    int bh = b2 * HEADS + h;
    float a0 = 0.f, a1 = 0.f, a2 = 0.f, a3 = 0.f, l = 0.f;
    #pragma unroll
    for (int ks = 0; ks < KSPLIT; ks++) {
        bf16x4 p = *(const bf16x4*)&opart[((size_t)ks * MTOT + token) * DIM + c];
        a0 += (float)p[0]; a1 += (float)p[1]; a2 += (float)p[2]; a3 += (float)p[3];
        l += lpart[((size_t)ks * 12 + bh) * NTOK + n];
    }
    float inv = 1.f / l;
    bf16x4 ov = { (__bf16)(a0 * inv), (__bf16)(a1 * inv),
                  (__bf16)(a2 * inv), (__bf16)(a3 * inv) };
    *(bf16x4*)(o + (size_t)token * DIM + c) = ov;
}

// ---------------------------------------------------------------------------
extern "C" void kernel_launch(void* const* d_in, const int* in_sizes, int n_in,
                              void* d_out, int out_size, void* d_ws, size_t ws_size,
                              hipStream_t stream) {
    const float* x      = (const float*)d_in[0];
    const float* conv_w = (const float*)d_in[1];
    // d_in[2] conv_b cancels in reference
    const float* ln1_w  = (const float*)d_in[3];
    const float* ln1_b  = (const float*)d_in[4];
    const float* qkv_w  = (const float*)d_in[5];
    const float* proj_w = (const float*)d_in[6];
    const float* proj_b = (const float*)d_in[7];
    const float* ln2_w  = (const float*)d_in[8];
    const float* ln2_b  = (const float*)d_in[9];
    const float* fc1_w  = (const float*)d_in[10];
    const float* fc1_b  = (const float*)d_in[11];
    const float* fc2_w  = (const float*)d_in[12];
    const float* fc2_b  = (const float*)d_in[13];
    float* out = (float*)d_out;

    char* p = (char*)d_ws;
    float*  T    = (float*)p;  p += (size_t)MTOT * DIM * 4;          //  8.4 MB
    __bf16* TN   = (__bf16*)p; p += (size_t)MTOT * DIM * 2;          //  4.2 MB
    __bf16* QKV  = (__bf16*)p; p += (size_t)MTOT * 1152 * 2;         // 12.6 MB
    __bf16* VT   = (__bf16*)p; p += (size_t)BATCH * DIM * NTOK * 2;  //  4.2 MB
    __bf16* O    = (__bf16*)p; p += (size_t)MTOT * DIM * 2;          //  4.2 MB
    __bf16* H    = (__bf16*)p; p += (size_t)MTOT * HIDDEN * 2;       // 16.9 MB
    __bf16* WQ   = (__bf16*)p; p += (size_t)1152 * 384 * 2;
    __bf16* WP   = (__bf16*)p; p += (size_t)384 * 384 * 2;
    __bf16* W1   = (__bf16*)p; p += (size_t)1536 * 384 * 2;
    __bf16* W2   = (__bf16*)p; p += (size_t)384 * 1536 * 2;
    float*  LP   = (float*)p;  p += (size_t)KSPLIT * 12 * NTOK * 4;
    __bf16* OP   = (__bf16*)p; p += (size_t)KSPLIT * MTOT * DIM * 2; // 16.9 MB

    // 1. conv positional embedding + residual (write-combined) + weight cvt
    k_conv<<<528 + 1728, 256, 0, stream>>>(
        x, conv_w, T, qkv_w, proj_w, fc1_w, fc2_w, WQ, WP, W1, W2);
    // 2. LN1 -> bf16
    k_ln1<<<MTOT / 4, 256, 0, stream>>>(T, TN, ln1_w, ln1_b);
    // 3. QKV gemm (128x64 single-buffer): Q pre-scaled; V -> VT transposed
    k_qkv<<<dim3(18, 43), 256, 0, stream>>>(TN, WQ, QKV, VT, MTOT, 1152, 384);
    // 4. attention split-K partials (bf16) + combine -> O bf16
    k_attn<<<dim3(NQT, 12, KSPLIT), 256, 0, stream>>>(QKV, VT, OP, LP);
    k_comb<<<(MTOT * 96) / 256, 256, 0, stream>>>(OP, LP, O);
    // 5. T += O @ proj_w^T + proj_b (64x64 single-buffer)
    k_proj<<<dim3(6, 86), 256, 0, stream>>>(O, WP, proj_b, T, T, MTOT, 384, 384);
    // 6. LN2 -> bf16
    k_ln2<<<MTOT / 4, 256, 0, stream>>>(T, TN, ln2_w, ln2_b);
    // 7. H = gelu(TN @ fc1_w^T + fc1_b) bf16 (128x64 single-buffer)
    k_fc1<<<dim3(24, 43), 256, 0, stream>>>(TN, W1, fc1_b, H, MTOT, 1536, 384);
    // 8. out[b,c,n] = T + H @ fc2_w^T + fc2_b (LDS-transposed coalesced store)
    k_fc2<<<dim3(6, 86), 256, 0, stream>>>(H, W2, fc2_b, T, out, MTOT, 384, 1536);
}